// Round 6
// baseline (87.793 us; speedup 1.0000x reference)
//
#include <hip/hip_runtime.h>

#define NN 256     // Preisach mesh size
#define TT 32      // outputs (steps) per chunk; G = ceil(M/TT) = 125 for M=4000
                   // NOTE: requires G <= NN (holds for M <= 8192)

__device__ __forceinline__ float softplus_f(float x) {
    if (x > 20.0f) return x;
    return log1pf(expf(x));
}

__device__ __forceinline__ unsigned magicP(int i) { return 0x5bd1e995u * (unsigned)(i + 17); }
__device__ __forceinline__ unsigned magicU(int i) { return 0x9E3779B9u * (unsigned)(i + 29); }

// Single launch. Block b (0..255):
//   Phase P: PrefT column b (prefix of softplus row b, transposed store) -> flag readyP[b].
//   Blocks b < G continue as chunk c=b:
//   Phase T: chunk step table + own UDt row (r0 kA code) -> flag readyU[c].
//   Wait:    poll readyP[0..255] + readyU[0..c-1] in parallel, then acquire fence.
//   Phase W: ILP-32 carry scan over UDt + 32-step walk + reduce (r0 kB code).
__global__ void __launch_bounds__(256, 2)
kOne(const float* __restrict__ h_g, const float* __restrict__ raw,
     float* __restrict__ out, int M, int G,
     float* __restrict__ PrefT, float* __restrict__ RowTot, unsigned* __restrict__ UDt,
     unsigned* __restrict__ readyP, unsigned* __restrict__ readyU)
{
    __shared__ float xs[NN];
    __shared__ float hh[TT + 1];
    __shared__ int   dd[TT + 1];
    __shared__ int   rec_s[TT + 1];
    __shared__ int   Dv[NN];
    __shared__ float red[4 * (TT + 2)];
    __shared__ float tot[TT + 2];
    __shared__ float wsum[4];

    const int b = blockIdx.x, tid = threadIdx.x;
    const int lane = tid & 63, wv = tid >> 6;

    // ---------------- Phase P: PrefT column b (verified r3 scan) ----------------
    {
        float x = 0.0f;
        if (tid <= b) x = softplus_f(raw[b * (b + 1) / 2 + tid]);
        #pragma unroll
        for (int off = 1; off <= 32; off <<= 1) {
            float y = __shfl_up(x, off, 64);
            if (lane >= off) x += y;
        }
        if (lane == 63) wsum[wv] = x;
        __syncthreads();
        float add = 0.0f;
        if (wv > 0) add += wsum[0];
        if (wv > 1) add += wsum[1];
        if (wv > 2) add += wsum[2];
        x += add;
        PrefT[(tid + 1) * NN + b] = x;             // PrefT[k][i], k=0..256
        if (tid == 0)      PrefT[b] = 0.0f;        // k=0 row, element i=b
        if (tid == NN - 1) RowTot[b] = x;
        __syncthreads();                            // all column writes done
        if (tid == 0) {
            __threadfence();                        // device-visible (cross-XCD)
            __hip_atomic_store(&readyP[b], magicP(b), __ATOMIC_RELAXED, __HIP_MEMORY_SCOPE_AGENT);
        }
    }
    if (b >= G) return;

    // ---------------- Phase T: chunk table + own UDt row (verified r0 kA) -------
    const int c  = b;
    const int t0 = c * TT;
    const int Tb = min(TT, M - t0);

    xs[tid] = (float)((double)tid / 255.0);        // np.linspace(0,1,256) f64->f32
    if (tid < TT) { rec_s[1 + tid] = 0; dd[1 + tid] = 0; }
    __syncthreads();
    if (tid < Tb) {
        int tau = t0 + 1 + tid;
        float cur  = (h_g[tau - 1] + 1.0f) * 0.5f;
        float prev = (tau == 1) ? 1.0f : (h_g[tau - 2] + 1.0f) * 0.5f;
        int d = (cur > prev) ? 2 : ((cur < prev) ? 0 : 1);
        int lo = 0, hi = NN;                       // ih = #{x < cur}
        while (lo < hi) { int m = (lo + hi) >> 1; if (xs[m] < cur) lo = m + 1; else hi = m; }
        int ih = lo;
        lo = 0; hi = NN;                           // jh = #{x <= cur}
        while (lo < hi) { int m = (lo + hi) >> 1; if (xs[m] <= cur) lo = m + 1; else hi = m; }
        int jh = lo;
        hh[1 + tid] = cur;
        dd[1 + tid] = d - 1;
        rec_s[1 + tid] = d | (ih << 2) | (jh << 11);
    }
    __syncthreads();
    {
        float xi = xs[tid];
        int Ue0 = 0, De0 = 0;                      // absolute tau+1, 0 = none
        for (int k = 1; k <= Tb; ++k) {
            float hv = hh[k]; int d = dd[k];
            if (d > 0 && hv > xi) Ue0 = t0 + k + 1;
            if (d < 0 && hv < xi) De0 = t0 + k + 1;
        }
        UDt[c * NN + tid] = (unsigned)Ue0 | ((unsigned)De0 << 16);
    }
    __syncthreads();
    if (tid == 0) {
        __threadfence();
        __hip_atomic_store(&readyU[c], magicU(c), __ATOMIC_RELAXED, __HIP_MEMORY_SCOPE_AGENT);
    }

    // ---------------- Wait: all PrefT flags + UDt flags of chunks < c ------------
    {
        int guard = 0;
        for (;;) {
            unsigned pv = __hip_atomic_load(&readyP[tid], __ATOMIC_RELAXED, __HIP_MEMORY_SCOPE_AGENT);
            int ok = (pv == magicP(tid));
            if (ok && tid < c) {
                unsigned uv = __hip_atomic_load(&readyU[tid], __ATOMIC_RELAXED, __HIP_MEMORY_SCOPE_AGENT);
                ok = (uv == magicU(tid));
            }
            if (__syncthreads_and(ok)) break;
            if (++guard > (1 << 27)) break;        // safety valve: terminate, never hang
        }
        __threadfence();                           // acquire: discard stale cached lines
    }

    // ---------------- Phase W: carry scan + walk + reduce (verified r0 kB) -------
    float RT = RowTot[tid];

    float hsM = (h_g[M - 1] + 1.0f) * 0.5f;        // hs[M] (roll wrap)
    unsigned uM = (hsM < 1.0f && tid < NN - 1) ? 1u : 0u;
    unsigned dM = 0u;
    const unsigned* p = UDt + tid;
    for (int k = 0; k < c; k += 32) {              // ILP-32; clamp dup harmless (max)
        unsigned vv[32];
        #pragma unroll
        for (int u = 0; u < 32; ++u) {
            int idx = k + u; if (idx >= c) idx = c - 1;
            vv[u] = p[idx * NN];
        }
        #pragma unroll
        for (int u = 0; u < 32; ++u) {
            unsigned ue = vv[u] & 0xFFFFu, de = vv[u] >> 16;
            if (ue > uM) uM = ue;
            if (de > dM) dM = de;
        }
    }
    int Ue = (int)uM;
    Dv[tid] = (int)dM;
    __syncthreads();

    // prefetch PrefT rows for each step's jh (coalesced)
    float pk[TT + 1];
    #pragma unroll
    for (int kk = 1; kk <= TT; ++kk) {
        int jh = (rec_s[kk] >> 11) & 0x1FF;
        pk[kk] = PrefT[jh * NN + tid];
    }

    // cix = #{j : De_j < Ue} (Dv non-decreasing), clamp to triangle
    int lo = 0, hi = NN;
    while (lo < hi) { int m = (lo + hi) >> 1; if (Dv[m] < Ue) lo = m + 1; else hi = m; }
    int cix = min(lo, tid + 1);
    float w = 2.0f * PrefT[cix * NN + tid] - RT;

    // barrier-free walk: per-thread deltas per step
    float vals[TT + 2];
    vals[0] = RT; vals[1] = w;
    int cc = cix; float ww = w;
    #pragma unroll
    for (int kk = 1; kk <= TT; ++kk) {
        float dl = 0.0f;
        if (kk <= Tb) {
            int rec = rec_s[kk];
            int d = rec & 3;
            if (d == 2) {                          // up: rows i < ih -> +RowTot
                int ih = (rec >> 2) & 0x1FF;
                if (tid < ih) { dl = RT - ww; ww = RT; cc = tid + 1; }
            } else if (d == 0) {                   // down: truncate prefix to jh
                int jh = (rec >> 11) & 0x1FF;
                if (cc > jh) { float wn = 2.0f * pk[kk] - RT; dl = wn - ww; ww = wn; cc = jh; }
            }
        }
        vals[1 + kk] = dl;
    }

    // reduce all TT+2 quantities: wave shuffle then cross-wave via LDS
    #pragma unroll
    for (int q = 0; q < TT + 2; ++q)
        for (int off = 32; off; off >>= 1)
            vals[q] += __shfl_down(vals[q], off, 64);
    if (lane == 0) {
        #pragma unroll
        for (int q = 0; q < TT + 2; ++q) red[wv * (TT + 2) + q] = vals[q];
    }
    __syncthreads();
    if (tid < TT + 2)
        tot[tid] = red[tid] + red[(TT + 2) + tid] + red[2 * (TT + 2) + tid] + red[3 * (TT + 2) + tid];
    __syncthreads();
    if (tid < TT) {                                // 32-lane shuffle prefix-scan
        float x = tot[2 + tid];
        #pragma unroll
        for (int off = 1; off < TT; off <<= 1) {
            float y = __shfl_up(x, off, 64);
            if (tid >= off) x += y;
        }
        if (tid < Tb) out[t0 + tid] = (tot[1] + x) * (1.0f / tot[0]);
    }
}

extern "C" void kernel_launch(void* const* d_in, const int* in_sizes, int n_in,
                              void* d_out, int out_size, void* d_ws, size_t ws_size,
                              hipStream_t stream) {
    const float* h   = (const float*)d_in[0];
    const float* raw = (const float*)d_in[1];
    float* out = (float*)d_out;
    int M = in_sizes[0];            // 4000
    int G = (M + TT - 1) / TT;      // 125 chunks (<= NN required)

    char* ws = (char*)d_ws;
    size_t off = 0;
    auto take = [&](size_t bytes) { size_t cur = off; off = (off + bytes + 255) & ~(size_t)255; return cur; };
    float*    PrefT  = (float*)(ws + take((size_t)(NN + 1) * NN * 4));
    float*    RowTot = (float*)(ws + take((size_t)NN * 4));
    unsigned* UDt    = (unsigned*)(ws + take((size_t)G * NN * 4));
    unsigned* readyP = (unsigned*)(ws + take((size_t)NN * 4));
    unsigned* readyU = (unsigned*)(ws + take((size_t)G * 4));

    kOne<<<NN, 256, 0, stream>>>(h, raw, out, M, G, PrefT, RowTot, UDt, readyP, readyU);
}

// Round 7
// 69.041 us; speedup vs baseline: 1.2716x; 1.2716x over previous
//
#include <hip/hip_runtime.h>

#define NN 256     // Preisach mesh size
#define TT 32      // outputs (steps) per chunk
// G = ceil(M/TT) = 125 chunks for M=4000

__device__ __forceinline__ float softplus_f(float x) {
    if (x > 20.0f) return x;
    return log1pf(expf(x));
}

// ---- kA: fused. Blocks [0,NN): prefix rows of dens (transposed store).
//          Blocks [NN, NN+G): chunk tables (packed step records + last-flip).
__global__ void __launch_bounds__(256)
kA(const float* __restrict__ h_g, const float* __restrict__ raw, int M, int G,
   float* __restrict__ PrefT, float* __restrict__ RowTot,
   int* __restrict__ steps_g, unsigned int* __restrict__ UDt)
{
    int b = blockIdx.x, tid = threadIdx.x;
    if (b < NN) {
        // per-row prefix sums of dens = softplus(raw) on lower triangle.
        // Intra-wave shuffle scan + cross-wave via wave totals (verified r3/r5),
        // 1 barrier instead of 16.
        __shared__ float wsum[4];
        float x = 0.0f;
        if (tid <= b) x = softplus_f(raw[b * (b + 1) / 2 + tid]);
        int lane = tid & 63, wv = tid >> 6;
        #pragma unroll
        for (int off = 1; off <= 32; off <<= 1) {
            float y = __shfl_up(x, off, 64);
            if (lane >= off) x += y;
        }
        if (lane == 63) wsum[wv] = x;
        __syncthreads();
        float add = 0.0f;
        if (wv > 0) add += wsum[0];
        if (wv > 1) add += wsum[1];
        if (wv > 2) add += wsum[2];
        x += add;
        PrefT[(tid + 1) * NN + b] = x;             // PrefT[k][i], k=0..256
        if (tid == 0)      PrefT[b] = 0.0f;
        if (tid == NN - 1) RowTot[b] = x;
    } else {
        // chunk c: steps tau in [t0+1, t0+Tb]  (byte-identical r0)
        __shared__ float xs[NN];
        __shared__ float hh[TT + 1];
        __shared__ int   dd[TT + 1];
        int c  = b - NN;
        int t0 = c * TT;
        int Tb = min(TT, M - t0);
        xs[tid] = (float)((double)tid / 255.0);    // np.linspace(0,1,256) f64->f32
        __syncthreads();
        if (tid < Tb) {
            int tau = t0 + 1 + tid;
            float cur  = (h_g[tau - 1] + 1.0f) * 0.5f;
            float prev = (tau == 1) ? 1.0f : (h_g[tau - 2] + 1.0f) * 0.5f;
            int d = (cur > prev) ? 2 : ((cur < prev) ? 0 : 1);
            int lo = 0, hi = NN;                   // ih = #{x < cur}
            while (lo < hi) { int m = (lo + hi) >> 1; if (xs[m] < cur) lo = m + 1; else hi = m; }
            int ih = lo;
            lo = 0; hi = NN;                       // jh = #{x <= cur}
            while (lo < hi) { int m = (lo + hi) >> 1; if (xs[m] <= cur) lo = m + 1; else hi = m; }
            int jh = lo;
            hh[1 + tid] = cur;
            dd[1 + tid] = d - 1;
            steps_g[tau] = d | (ih << 2) | (jh << 11);
        }
        __syncthreads();
        float xi = xs[tid];
        int Ue = 0, De = 0;                        // absolute tau+1, 0 = none
        for (int k = 1; k <= Tb; ++k) {
            float hv = hh[k]; int d = dd[k];
            if (d > 0 && hv > xi) Ue = t0 + k + 1;
            if (d < 0 && hv < xi) De = t0 + k + 1;
        }
        UDt[c * NN + tid] = (unsigned)Ue | ((unsigned)De << 16);  // chunk-major
    }
}

// ---- kB: per-chunk carry-in (ILP-32 max-scan over prior chunks) + walk ----
__global__ void __launch_bounds__(256)
kB(const float* __restrict__ h_g, const int* __restrict__ steps_g,
   const unsigned int* __restrict__ UDt,
   const float* __restrict__ PrefT, const float* __restrict__ RowTot,
   float* __restrict__ out, int M)
{
    __shared__ int   rec_s[TT + 1];
    __shared__ int   Dv[NN];
    __shared__ float red[4 * (TT + 2)];
    __shared__ float tot[TT + 2];
    int b = blockIdx.x, tid = threadIdx.x;
    int t0 = b * TT;
    int Tb = min(TT, M - t0);

    if (tid < TT) rec_s[1 + tid] = (tid < Tb) ? steps_g[t0 + 1 + tid] : 0;
    float RT = RowTot[tid];

    // carry-in: tau=0 step (h = 1.0) then max over previous chunk tables.
    // ILP-32 with clamp-dup (verified r6 phase W): 4 latency rounds worst-case.
    float hsM = (h_g[M - 1] + 1.0f) * 0.5f;        // hs[M] (roll wrap)
    unsigned uM = (hsM < 1.0f && tid < NN - 1) ? 1u : 0u;
    unsigned dM = 0u;
    const unsigned int* p = UDt + tid;
    for (int k = 0; k < b; k += 32) {              // dup of last row harmless (max)
        unsigned vv[32];
        #pragma unroll
        for (int u = 0; u < 32; ++u) {
            int idx = k + u; if (idx >= b) idx = b - 1;
            vv[u] = p[idx * NN];
        }
        #pragma unroll
        for (int u = 0; u < 32; ++u) {
            unsigned ue = vv[u] & 0xFFFFu, de = vv[u] >> 16;
            if (ue > uM) uM = ue;
            if (de > dM) dM = de;
        }
    }
    int Ue = (int)uM;
    Dv[tid] = (int)dM;
    __syncthreads();

    // prefetch PrefT rows for each step's jh (coalesced)
    float pk[TT + 1];
    #pragma unroll
    for (int kk = 1; kk <= TT; ++kk) {
        int jh = (rec_s[kk] >> 11) & 0x1FF;
        pk[kk] = PrefT[jh * NN + tid];
    }

    // c = #{j : De_j < Ue} (Dv non-decreasing), clamp to triangle
    int lo = 0, hi = NN;
    while (lo < hi) { int m = (lo + hi) >> 1; if (Dv[m] < Ue) lo = m + 1; else hi = m; }
    int c = min(lo, tid + 1);
    float w = 2.0f * PrefT[c * NN + tid] - RT;

    // barrier-free walk: per-thread deltas per step
    float vals[TT + 2];
    vals[0] = RT; vals[1] = w;
    int cc = c; float ww = w;
    #pragma unroll
    for (int kk = 1; kk <= TT; ++kk) {
        float dl = 0.0f;
        if (kk <= Tb) {
            int rec = rec_s[kk];
            int d = rec & 3;
            if (d == 2) {                          // up: rows i < ih -> +RowTot
                int ih = (rec >> 2) & 0x1FF;
                if (tid < ih) { dl = RT - ww; ww = RT; cc = tid + 1; }
            } else if (d == 0) {                   // down: truncate prefix to jh
                int jh = (rec >> 11) & 0x1FF;
                if (cc > jh) { float wn = 2.0f * pk[kk] - RT; dl = wn - ww; ww = wn; cc = jh; }
            }
        }
        vals[1 + kk] = dl;
    }

    // reduce all TT+2 quantities: wave shuffle then cross-wave via LDS
    #pragma unroll
    for (int q = 0; q < TT + 2; ++q)
        for (int off = 32; off; off >>= 1)
            vals[q] += __shfl_down(vals[q], off, 64);
    int lane = tid & 63, wv = tid >> 6;
    if (lane == 0) {
        #pragma unroll
        for (int q = 0; q < TT + 2; ++q) red[wv * (TT + 2) + q] = vals[q];
    }
    __syncthreads();
    if (tid < TT + 2)
        tot[tid] = red[tid] + red[(TT + 2) + tid] + red[2 * (TT + 2) + tid] + red[3 * (TT + 2) + tid];
    __syncthreads();
    if (tid < TT) {                                // 32-lane shuffle prefix-scan
        float x = tot[2 + tid];
        #pragma unroll
        for (int off = 1; off < TT; off <<= 1) {
            float y = __shfl_up(x, off, 64);
            if (tid >= off) x += y;
        }
        if (tid < Tb) out[t0 + tid] = (tot[1] + x) * (1.0f / tot[0]);
    }
}

extern "C" void kernel_launch(void* const* d_in, const int* in_sizes, int n_in,
                              void* d_out, int out_size, void* d_ws, size_t ws_size,
                              hipStream_t stream) {
    const float* h   = (const float*)d_in[0];
    const float* raw = (const float*)d_in[1];
    float* out = (float*)d_out;
    int M = in_sizes[0];            // 4000
    int G = (M + TT - 1) / TT;      // 125 chunks

    char* ws = (char*)d_ws;
    size_t off = 0;
    auto take = [&](size_t bytes) { size_t cur = off; off = (off + bytes + 255) & ~(size_t)255; return cur; };
    float*        PrefT  = (float*)(ws + take((size_t)(NN + 1) * NN * 4));
    float*        RowTot = (float*)(ws + take((size_t)NN * 4));
    int*          steps  = (int*)(ws + take((size_t)(M + 1) * 4));
    unsigned int* UDt    = (unsigned int*)(ws + take((size_t)G * NN * 4));

    kA<<<NN + G, 256, 0, stream>>>(h, raw, M, G, PrefT, RowTot, steps, UDt);
    kB<<<G, 256, 0, stream>>>(h, steps, UDt, PrefT, RowTot, out, M);
}